// Round 9
// baseline (596.871 us; speedup 1.0000x reference)
//
#include <hip/hip_runtime.h>
#include <math.h>

#define N_NODES 50000
#define N_EDGES 800000
#define IN_DIM 256
#define HID 32
#define HEADS 8
#define OUT_DIM 64
#define NEG_SLOPE 0.2f

typedef short bf16x8 __attribute__((ext_vector_type(8)));
typedef float f32x4 __attribute__((ext_vector_type(4)));

static __device__ __forceinline__ float lrelu(float v) {
    return v > 0.f ? v : NEG_SLOPE * v;
}
static __device__ __forceinline__ float elu_f(float v) {
    return v > 0.f ? v : (__expf(v) - 1.f);
}
static __device__ __forceinline__ unsigned short f2bf(float f) {
    unsigned int u = __float_as_uint(f);
    u = (u + 0x7FFFu + ((u >> 16) & 1u)) >> 16;  // RNE
    return (unsigned short)u;
}
static __device__ __forceinline__ float bf2f(unsigned short b) {
    return __uint_as_float(((unsigned int)b) << 16);
}

// ---------------- CSR build ----------------

__global__ void hist_kernel(const int* __restrict__ dst, int* __restrict__ cnt, int e) {
    int i = blockIdx.x * blockDim.x + threadIdx.x;
    if (i < e) atomicAdd(&cnt[dst[i]], 1);
}

__global__ __launch_bounds__(1024) void scan_fast(const int* __restrict__ counts,
                                                  int* __restrict__ offsets,
                                                  int* __restrict__ cursor, int n) {
    __shared__ int part[1024];
    int t = threadIdx.x;
    int chunk = (n + 1023) >> 10;
    int beg = t * chunk;
    int end = beg + chunk;
    if (end > n) end = n;
    int s = 0;
    for (int i = beg; i < end; ++i) s += counts[i];
    part[t] = s;
    __syncthreads();
    for (int off = 1; off < 1024; off <<= 1) {
        int v = (t >= off) ? part[t - off] : 0;
        __syncthreads();
        part[t] += v;
        __syncthreads();
    }
    int run = (t > 0) ? part[t - 1] : 0;
    for (int i = beg; i < end; ++i) {
        int c = counts[i];
        offsets[i] = run;
        cursor[i] = run;
        run += c;
    }
    if (t == 1023) offsets[n] = part[1023];
}

__global__ void scatter_kernel(const int* __restrict__ src, const int* __restrict__ dst,
                               int* __restrict__ cursor, int* __restrict__ csr_src, int e) {
    int i = blockIdx.x * blockDim.x + threadIdx.x;
    if (i < e) {
        int p = atomicAdd(&cursor[dst[i]], 1);
        csr_src[p] = src[i];
    }
}

// ---------------- X hi/lo bf16 split ----------------

__global__ void presplit(const float* __restrict__ x, unsigned short* __restrict__ hi,
                         unsigned short* __restrict__ lo, int n4) {
    int i = blockIdx.x * blockDim.x + threadIdx.x;
    if (i >= n4) return;
    float4 v = ((const float4*)x)[i];
    ushort4 h, lw;
    h.x = f2bf(v.x); lw.x = f2bf(v.x - bf2f(h.x));
    h.y = f2bf(v.y); lw.y = f2bf(v.y - bf2f(h.y));
    h.z = f2bf(v.z); lw.z = f2bf(v.z - bf2f(h.z));
    h.w = f2bf(v.w); lw.w = f2bf(v.w - bf2f(h.w));
    ((ushort4*)hi)[i] = h;
    ((ushort4*)lo)[i] = lw;
}

// ---------------- W fragment packing (hi/lo) ----------------
// frag idx t = (((mat*2+p)*16 + nt)*8 + ks)*64 + l ; element j in [0,8).
// value = split_p( W[ks*32 + 8*(l>>4) + j][nt*16 + (l&15)] ).
// NEEDS 2*2*16*8*64 = 32768 threads.

__global__ void wprep(const float* __restrict__ Wl, const float* __restrict__ Wr,
                      unsigned short* __restrict__ Wfrag) {
    int t = blockIdx.x * blockDim.x + threadIdx.x;  // 32768 total
    int l = t & 63;
    int ks = (t >> 6) & 7;
    int nt = (t >> 9) & 15;
    int p = (t >> 13) & 1;
    int mat = (t >> 14) & 1;
    const float* W = mat ? Wr : Wl;
    int col = nt * 16 + (l & 15);
    int kb = ks * 32 + ((l >> 4) << 3);
    unsigned short* dst = Wfrag + (size_t)t * 8;
#pragma unroll
    for (int j = 0; j < 8; ++j) {
        float w = W[(size_t)(kb + j) * 256 + col];
        unsigned short h = f2bf(w);
        dst[j] = p ? f2bf(w - bf2f(h)) : h;
    }
}

// ---------------- conv1 GEMM on MFMA (split-bf16, ~fp32 accurate) ----------------
// grid (ceil(M/32), 2). Block 256 = 4 waves; wave w owns cols [w*64, w*64+64).
// Per wave: 2 M-tiles x 4 N-tiles of 16x16, K=256 in 8 steps of 32.
// acc = 32 AGPR; total regs ~110 -> 4 waves/SIMD (TLP hides load latency; no barriers).

__global__ __launch_bounds__(256) void gemm_conv1_mfma(
    const unsigned short* __restrict__ Xhi, const unsigned short* __restrict__ Xlo,
    const unsigned short* __restrict__ Wfrag,
    const float* __restrict__ bl, const float* __restrict__ br,
    unsigned short* __restrict__ Ylb, float* __restrict__ Yr, int M) {
    int tid = threadIdx.x;
    int wv = tid >> 6, l = tid & 63;
    int mat = blockIdx.y;
    int row0 = blockIdx.x * 32;
    int lrow = l & 15;
    int kg = (l >> 4) << 3;  // 0,8,16,24

    f32x4 acc[2][4];
#pragma unroll
    for (int i = 0; i < 2; ++i)
#pragma unroll
        for (int j = 0; j < 4; ++j) acc[i][j] = (f32x4){0.f, 0.f, 0.f, 0.f};

    size_t arow[2];
#pragma unroll
    for (int mt = 0; mt < 2; ++mt) {
        int r = row0 + mt * 16 + lrow;
        if (r > M - 1) r = M - 1;
        arow[mt] = (size_t)r * 256;
    }
    const bf16x8* bp = (const bf16x8*)Wfrag;
    size_t bhiB = ((size_t)(mat * 2 + 0) * 16 + wv * 4) * 8 * 64 + l;
    size_t bloB = ((size_t)(mat * 2 + 1) * 16 + wv * 4) * 8 * 64 + l;

    for (int ks = 0; ks < 8; ++ks) {
        int k0 = ks * 32 + kg;
        bf16x8 ah[2], al[2], bh[4], bw[4];
#pragma unroll
        for (int mt = 0; mt < 2; ++mt) {
            ah[mt] = *(const bf16x8*)(Xhi + arow[mt] + k0);
            al[mt] = *(const bf16x8*)(Xlo + arow[mt] + k0);
        }
#pragma unroll
        for (int nt = 0; nt < 4; ++nt) {
            bh[nt] = bp[bhiB + ((size_t)nt * 8 + ks) * 64];
            bw[nt] = bp[bloB + ((size_t)nt * 8 + ks) * 64];
        }
#pragma unroll
        for (int mt = 0; mt < 2; ++mt)
#pragma unroll
            for (int nt = 0; nt < 4; ++nt) {
                acc[mt][nt] = __builtin_amdgcn_mfma_f32_16x16x32_bf16(ah[mt], bh[nt], acc[mt][nt], 0, 0, 0);
                acc[mt][nt] = __builtin_amdgcn_mfma_f32_16x16x32_bf16(ah[mt], bw[nt], acc[mt][nt], 0, 0, 0);
                acc[mt][nt] = __builtin_amdgcn_mfma_f32_16x16x32_bf16(al[mt], bh[nt], acc[mt][nt], 0, 0, 0);
            }
    }

    const float* bias = mat ? br : bl;
    int col_l = l & 15;
    int rbase = (l >> 4) << 2;
#pragma unroll
    for (int nt = 0; nt < 4; ++nt) {
        int col = wv * 64 + nt * 16 + col_l;
        float bv = bias[col];
#pragma unroll
        for (int mt = 0; mt < 2; ++mt)
#pragma unroll
            for (int r = 0; r < 4; ++r) {
                int row = row0 + mt * 16 + rbase + r;
                if (row < M) {
                    float v = acc[mt][nt][r] + bv;
                    if (mat == 0)
                        Ylb[(size_t)row * 256 + col] = f2bf(v);
                    else
                        Yr[(size_t)row * 256 + col] = v;
                }
            }
    }
}

// ---------------- conv2 GEMM: X[M x 256] @ {Wl,Wr}[256 x 32] ----------------
// Yl written as bf16 (gathered operand of conv2), Yr fp32.

__global__ __launch_bounds__(256) void gemm_dual_32(
    const float* __restrict__ X,
    const float* __restrict__ Wl, const float* __restrict__ bl,
    const float* __restrict__ Wr, const float* __restrict__ br,
    unsigned short* __restrict__ Ylb, float* __restrict__ Yr, int M) {
    __shared__ float As[16][68];
    __shared__ float B2l[16][36];
    __shared__ float B2r[16][36];
    int tid = threadIdx.x;
    int tx = tid & 31;
    int ty = tid >> 5;
    int row0 = blockIdx.x * 64;
    float accl[8] = {0.f};
    float accr[8] = {0.f};
    int ar = tid >> 2;
    int ak = (tid & 3) << 2;

    for (int k0 = 0; k0 < 256; k0 += 16) {
        float4 av = make_float4(0.f, 0.f, 0.f, 0.f);
        if (row0 + ar < M)
            av = *(const float4*)(X + (size_t)(row0 + ar) * 256 + k0 + ak);
        As[ak + 0][ar] = av.x;
        As[ak + 1][ar] = av.y;
        As[ak + 2][ar] = av.z;
        As[ak + 3][ar] = av.w;
        if (tid < 128) {
            int bk2 = tid >> 3, bn2 = (tid & 7) << 2;
            *(float4*)&B2l[bk2][bn2] = *(const float4*)(Wl + (size_t)(k0 + bk2) * 32 + bn2);
        } else {
            int t2 = tid - 128;
            int bk2 = t2 >> 3, bn2 = (t2 & 7) << 2;
            *(float4*)&B2r[bk2][bn2] = *(const float4*)(Wr + (size_t)(k0 + bk2) * 32 + bn2);
        }
        __syncthreads();
#pragma unroll
        for (int k = 0; k < 16; ++k) {
            float blv = B2l[k][tx];
            float brv = B2r[k][tx];
#pragma unroll
            for (int i = 0; i < 8; ++i) {
                float a = As[k][ty * 8 + i];
                accl[i] = fmaf(a, blv, accl[i]);
                accr[i] = fmaf(a, brv, accr[i]);
            }
        }
        __syncthreads();
    }
#pragma unroll
    for (int i = 0; i < 8; ++i) {
        int row = row0 + ty * 8 + i;
        if (row < M) {
            Ylb[(size_t)row * 32 + tx] = f2bf(accl[i] + bl[tx]);
            Yr[(size_t)row * 32 + tx] = accr[i] + br[tx];
        }
    }
}

// ---------------- conv1 attention/aggregation (bf16 gather, 8-deep) ----------------

__global__ __launch_bounds__(256) void conv1_agg(
    const unsigned short* __restrict__ xlb, const float* __restrict__ xr,
    const float* __restrict__ att, const float* __restrict__ bias,
    const int* __restrict__ offsets, const int* __restrict__ csr_src,
    float* __restrict__ hout, int n) {
    int g = (blockIdx.x * blockDim.x + threadIdx.x) >> 6;
    if (g >= n) return;
    int lane = threadIdx.x & 63;
    int c0 = lane << 2;
    float4 xr4 = *(const float4*)(xr + (size_t)g * 256 + c0);
    float4 at4 = *(const float4*)(att + c0);
    float4 bb = *(const float4*)(bias + c0);
    int beg = offsets[g], end = offsets[g + 1];
    float m = -INFINITY, denom = 0.f;
    float4 acc = make_float4(0.f, 0.f, 0.f, 0.f);
    const ushort4* xb = (const ushort4*)xlb;
    int j = beg;
    for (; j + 8 <= end; j += 8) {
        ushort4 q[8];
#pragma unroll
        for (int u = 0; u < 8; ++u) {
            int s = csr_src[j + u];
            q[u] = xb[((size_t)s << 6) + lane];
        }
        float4 a[8];
        float p[8];
#pragma unroll
        for (int u = 0; u < 8; ++u) {
            a[u] = make_float4(bf2f(q[u].x), bf2f(q[u].y), bf2f(q[u].z), bf2f(q[u].w));
            p[u] = at4.x * lrelu(a[u].x + xr4.x) + at4.y * lrelu(a[u].y + xr4.y) +
                   at4.z * lrelu(a[u].z + xr4.z) + at4.w * lrelu(a[u].w + xr4.w);
        }
#pragma unroll
        for (int d = 1; d < 8; d <<= 1)
#pragma unroll
            for (int u = 0; u < 8; ++u) p[u] += __shfl_xor(p[u], d);
        float mn = m;
#pragma unroll
        for (int u = 0; u < 8; ++u) mn = fmaxf(mn, p[u]);
        float f = __expf(m - mn);
        float e[8];
        float es = 0.f;
#pragma unroll
        for (int u = 0; u < 8; ++u) { e[u] = __expf(p[u] - mn); es += e[u]; }
        float sx = 0.f, sy = 0.f, sz = 0.f, sw = 0.f;
#pragma unroll
        for (int u = 0; u < 8; ++u) {
            sx = fmaf(e[u], a[u].x, sx);
            sy = fmaf(e[u], a[u].y, sy);
            sz = fmaf(e[u], a[u].z, sz);
            sw = fmaf(e[u], a[u].w, sw);
        }
        acc.x = fmaf(acc.x, f, sx);
        acc.y = fmaf(acc.y, f, sy);
        acc.z = fmaf(acc.z, f, sz);
        acc.w = fmaf(acc.w, f, sw);
        denom = fmaf(denom, f, es);
        m = mn;
    }
    for (; j < end; ++j) {
        int s = csr_src[j];
        ushort4 qq = xb[((size_t)s << 6) + lane];
        float4 a4 = make_float4(bf2f(qq.x), bf2f(qq.y), bf2f(qq.z), bf2f(qq.w));
        float p = at4.x * lrelu(a4.x + xr4.x) + at4.y * lrelu(a4.y + xr4.y) +
                  at4.z * lrelu(a4.z + xr4.z) + at4.w * lrelu(a4.w + xr4.w);
        p += __shfl_xor(p, 1);
        p += __shfl_xor(p, 2);
        p += __shfl_xor(p, 4);
        float mn = fmaxf(m, p);
        float f = __expf(m - mn);
        float e = __expf(p - mn);
        acc.x = fmaf(acc.x, f, e * a4.x);
        acc.y = fmaf(acc.y, f, e * a4.y);
        acc.z = fmaf(acc.z, f, e * a4.z);
        acc.w = fmaf(acc.w, f, e * a4.w);
        denom = fmaf(denom, f, e);
        m = mn;
    }
    float inv = 1.f / (denom + 1e-16f);
    float4 o;
    o.x = elu_f(fmaf(acc.x, inv, bb.x));
    o.y = elu_f(fmaf(acc.y, inv, bb.y));
    o.z = elu_f(fmaf(acc.z, inv, bb.z));
    o.w = elu_f(fmaf(acc.w, inv, bb.w));
    *(float4*)(hout + (size_t)g * 256 + c0) = o;
}

// ---------------- conv2 agg + ELU + final linear fused (bf16 gather, 8-deep) ----------------

__global__ __launch_bounds__(256) void conv2_final(
    const unsigned short* __restrict__ xlb, const float* __restrict__ xr,
    const float* __restrict__ att, const float* __restrict__ bias,
    const int* __restrict__ offsets, const int* __restrict__ csr_src,
    const float* __restrict__ Wlin, const float* __restrict__ blin,
    float* __restrict__ out, int n) {
    __shared__ float Ws[2048];  // Wlin 32x64
    int tid = threadIdx.x;
    ((float4*)Ws)[tid] = ((const float4*)Wlin)[tid];
    ((float4*)Ws)[tid + 256] = ((const float4*)Wlin)[tid + 256];
    __syncthreads();
    int g = (blockIdx.x * blockDim.x + tid) >> 5;
    if (g >= n) return;
    int sl = tid & 31;
    float xrv = xr[(size_t)g * 32 + sl];
    float atv = att[sl];
    float bv = bias[sl];
    int beg = offsets[g], end = offsets[g + 1];
    float m = -INFINITY, denom = 0.f, acc = 0.f;
    int j = beg;
    for (; j + 8 <= end; j += 8) {
        float a[8], p[8];
#pragma unroll
        for (int u = 0; u < 8; ++u) {
            int s = csr_src[j + u];
            a[u] = bf2f(xlb[(size_t)s * 32 + sl]);
        }
#pragma unroll
        for (int u = 0; u < 8; ++u) p[u] = atv * lrelu(a[u] + xrv);
#pragma unroll
        for (int d = 1; d < 32; d <<= 1)
#pragma unroll
            for (int u = 0; u < 8; ++u) p[u] += __shfl_xor(p[u], d);
        float mn = m;
#pragma unroll
        for (int u = 0; u < 8; ++u) mn = fmaxf(mn, p[u]);
        float f = __expf(m - mn);
        float es = 0.f, sa = 0.f;
#pragma unroll
        for (int u = 0; u < 8; ++u) {
            float e = __expf(p[u] - mn);
            es += e;
            sa = fmaf(e, a[u], sa);
        }
        acc = fmaf(acc, f, sa);
        denom = fmaf(denom, f, es);
        m = mn;
    }
    for (; j < end; ++j) {
        int s = csr_src[j];
        float a = bf2f(xlb[(size_t)s * 32 + sl]);
        float p = atv * lrelu(a + xrv);
        p += __shfl_xor(p, 1);
        p += __shfl_xor(p, 2);
        p += __shfl_xor(p, 4);
        p += __shfl_xor(p, 8);
        p += __shfl_xor(p, 16);
        float mn = fmaxf(m, p);
        float f = __expf(m - mn);
        float e = __expf(p - mn);
        acc = fmaf(acc, f, e * a);
        denom = fmaf(denom, f, e);
        m = mn;
    }
    float inv = 1.f / (denom + 1e-16f);
    float hval = elu_f(fmaf(acc, inv, bv));
    int j0 = sl << 1;
    float o0 = blin[j0], o1 = blin[j0 + 1];
#pragma unroll
    for (int k = 0; k < 32; ++k) {
        float hk = __shfl(hval, k, 32);
        float2 w2 = *(float2*)&Ws[k * 64 + j0];
        o0 = fmaf(hk, w2.x, o0);
        o1 = fmaf(hk, w2.y, o1);
    }
    *(float2*)(out + (size_t)g * 64 + j0) = make_float2(o0, o1);
}

// ---------------- launch ----------------

extern "C" void kernel_launch(void* const* d_in, const int* in_sizes, int n_in,
                              void* d_out, int out_size, void* d_ws, size_t ws_size,
                              hipStream_t stream) {
    const float* x    = (const float*)d_in[0];
    const int*   ei   = (const int*)d_in[1];
    const float* W1l  = (const float*)d_in[2];
    const float* b1l  = (const float*)d_in[3];
    const float* W1r  = (const float*)d_in[4];
    const float* b1r  = (const float*)d_in[5];
    const float* att1 = (const float*)d_in[6];
    const float* bias1= (const float*)d_in[7];
    const float* W2l  = (const float*)d_in[8];
    const float* b2l  = (const float*)d_in[9];
    const float* W2r  = (const float*)d_in[10];
    const float* b2r  = (const float*)d_in[11];
    const float* att2 = (const float*)d_in[12];
    const float* bias2= (const float*)d_in[13];
    const float* Wlin = (const float*)d_in[14];
    const float* blin = (const float*)d_in[15];
    float* out = (float*)d_out;

    char* p = (char*)d_ws;
    auto alloc = [&](size_t bytes) {
        char* r = p;
        p += (bytes + 255) & ~(size_t)255;
        return r;
    };
    int* offsets = (int*)alloc((size_t)(N_NODES + 1) * 4);
    int* cursor  = (int*)alloc((size_t)N_NODES * 4);  // doubles as counts
    int* csr_src = (int*)alloc((size_t)N_EDGES * 4);
    unsigned short* xl1b = (unsigned short*)alloc((size_t)N_NODES * 256 * 2);
    float* xr1 = (float*)alloc((size_t)N_NODES * 256 * 4);
    // X split region (dead after gemm_conv1_mfma) -> h1 aliases it
    unsigned short* xhi = (unsigned short*)alloc((size_t)N_NODES * 256 * 2);
    unsigned short* xlo = (unsigned short*)alloc((size_t)N_NODES * 256 * 2);
    unsigned short* wfrag = (unsigned short*)alloc((size_t)2 * 2 * 16 * 8 * 64 * 8 * 2);
    unsigned short* xl2b = (unsigned short*)alloc((size_t)N_NODES * 32 * 2);
    float* h1 = (float*)xhi;             // 51.2 MB alias over xhi+xlo
    float* xr2 = xr1;                    // xr1 dead after conv1_agg

    const int* srcp = ei;
    const int* dstp = ei + N_EDGES;

    hipMemsetAsync(cursor, 0, (size_t)N_NODES * 4, stream);
    hist_kernel<<<(N_EDGES + 255) / 256, 256, 0, stream>>>(dstp, cursor, N_EDGES);
    scan_fast<<<1, 1024, 0, stream>>>(cursor, offsets, cursor, N_NODES);
    scatter_kernel<<<(N_EDGES + 255) / 256, 256, 0, stream>>>(srcp, dstp, cursor, csr_src, N_EDGES);

    presplit<<<(N_NODES * 256 / 4 + 255) / 256, 256, 0, stream>>>(x, xhi, xlo, N_NODES * 256 / 4);
    wprep<<<128, 256, 0, stream>>>(W1l, W1r, wfrag);

    dim3 gg((N_NODES + 31) / 32, 2);
    gemm_conv1_mfma<<<gg, 256, 0, stream>>>(xhi, xlo, wfrag, b1l, b1r, xl1b, xr1, N_NODES);
    conv1_agg<<<(N_NODES * 64 + 255) / 256, 256, 0, stream>>>(xl1b, xr1, att1, bias1,
                                                              offsets, csr_src, h1, N_NODES);
    gemm_dual_32<<<(N_NODES + 63) / 64, 256, 0, stream>>>(h1, W2l, b2l, W2r, b2r, xl2b, xr2, N_NODES);
    conv2_final<<<(N_NODES * 32 + 255) / 256, 256, 0, stream>>>(xl2b, xr2, att2, bias2,
                                                                offsets, csr_src,
                                                                Wlin, blin, out, N_NODES);
}

// Round 10
// 493.516 us; speedup vs baseline: 1.2094x; 1.2094x over previous
//
#include <hip/hip_runtime.h>
#include <math.h>

#define N_NODES 50000
#define N_EDGES 800000
#define IN_DIM 256
#define HID 32
#define HEADS 8
#define OUT_DIM 64
#define NEG_SLOPE 0.2f
#define SCAN_NB ((N_NODES + 1023) / 1024)   // 49

typedef short bf16x8 __attribute__((ext_vector_type(8)));
typedef float f32x4 __attribute__((ext_vector_type(4)));

static __device__ __forceinline__ float lrelu(float v) {
    return v > 0.f ? v : NEG_SLOPE * v;
}
static __device__ __forceinline__ float elu_f(float v) {
    return v > 0.f ? v : (__expf(v) - 1.f);
}
static __device__ __forceinline__ unsigned short f2bf(float f) {
    unsigned int u = __float_as_uint(f);
    u = (u + 0x7FFFu + ((u >> 16) & 1u)) >> 16;  // RNE
    return (unsigned short)u;
}
static __device__ __forceinline__ float bf2f(unsigned short b) {
    return __uint_as_float(((unsigned int)b) << 16);
}

// ---------------- CSR build ----------------

__global__ void hist_kernel(const int* __restrict__ dst, int* __restrict__ cnt, int e) {
    int i = blockIdx.x * blockDim.x + threadIdx.x;
    if (i < e) atomicAdd(&cnt[dst[i]], 1);
}

// pass 1: per-block exclusive scan of counts -> offsets (block-local), block sums -> bsums
__global__ __launch_bounds__(1024) void scan_blk(const int* __restrict__ counts,
                                                 int* __restrict__ offsets,
                                                 int* __restrict__ bsums, int n) {
    __shared__ int buf[1024];
    int t = threadIdx.x;
    int i = blockIdx.x * 1024 + t;
    int v = (i < n) ? counts[i] : 0;
    buf[t] = v;
    __syncthreads();
    for (int off = 1; off < 1024; off <<= 1) {
        int add = (t >= off) ? buf[t - off] : 0;
        __syncthreads();
        buf[t] += add;
        __syncthreads();
    }
    if (i < n) offsets[i] = buf[t] - v;  // block-local exclusive
    if (t == 1023) bsums[blockIdx.x] = buf[1023];
}

// pass 2: one block scans the SCAN_NB block sums (exclusive) in place; bsums[nb] = total
__global__ __launch_bounds__(64) void scan_tops(int* __restrict__ bsums, int nb) {
    __shared__ int buf[64];
    int t = threadIdx.x;
    int v = (t < nb) ? bsums[t] : 0;
    buf[t] = v;
    __syncthreads();
    for (int off = 1; off < 64; off <<= 1) {
        int add = (t >= off) ? buf[t - off] : 0;
        __syncthreads();
        buf[t] += add;
        __syncthreads();
    }
    if (t < nb) bsums[t] = buf[t] - v;   // exclusive
    if (t == nb - 1) bsums[nb] = buf[t]; // total (inclusive at last)
}

// pass 3: add block base; mirror into cursor; write offsets[n]
__global__ __launch_bounds__(1024) void scan_add(const int* __restrict__ bsums,
                                                 int* __restrict__ offsets,
                                                 int* __restrict__ cursor, int n, int nb) {
    int t = threadIdx.x;
    int i = blockIdx.x * 1024 + t;
    if (i < n) {
        int o = offsets[i] + bsums[blockIdx.x];
        offsets[i] = o;
        cursor[i] = o;
    }
    if (i == 0) offsets[n] = bsums[nb];
}

__global__ void scatter_kernel(const int* __restrict__ src, const int* __restrict__ dst,
                               int* __restrict__ cursor, int* __restrict__ csr_src, int e) {
    int i = blockIdx.x * blockDim.x + threadIdx.x;
    if (i < e) {
        int p = atomicAdd(&cursor[dst[i]], 1);
        csr_src[p] = src[i];
    }
}

// ---------------- X hi/lo bf16 split ----------------

__global__ void presplit(const float* __restrict__ x, unsigned short* __restrict__ hi,
                         unsigned short* __restrict__ lo, int n4) {
    int i = blockIdx.x * blockDim.x + threadIdx.x;
    if (i >= n4) return;
    float4 v = ((const float4*)x)[i];
    ushort4 h, lw;
    h.x = f2bf(v.x); lw.x = f2bf(v.x - bf2f(h.x));
    h.y = f2bf(v.y); lw.y = f2bf(v.y - bf2f(h.y));
    h.z = f2bf(v.z); lw.z = f2bf(v.z - bf2f(h.z));
    h.w = f2bf(v.w); lw.w = f2bf(v.w - bf2f(h.w));
    ((ushort4*)hi)[i] = h;
    ((ushort4*)lo)[i] = lw;
}

// ---------------- W fragment packing (hi/lo) ----------------
// frag idx t = (((mat*2+p)*16 + nt)*8 + ks)*64 + l ; element j in [0,8).
// value = split_p( W[ks*32 + 8*(l>>4) + j][nt*16 + (l&15)] ).
// NEEDS 2*2*16*8*64 = 32768 threads.

__global__ void wprep(const float* __restrict__ Wl, const float* __restrict__ Wr,
                      unsigned short* __restrict__ Wfrag) {
    int t = blockIdx.x * blockDim.x + threadIdx.x;  // 32768 total
    int l = t & 63;
    int ks = (t >> 6) & 7;
    int nt = (t >> 9) & 15;
    int p = (t >> 13) & 1;
    int mat = (t >> 14) & 1;
    const float* W = mat ? Wr : Wl;
    int col = nt * 16 + (l & 15);
    int kb = ks * 32 + ((l >> 4) << 3);
    unsigned short* dst = Wfrag + (size_t)t * 8;
#pragma unroll
    for (int j = 0; j < 8; ++j) {
        float w = W[(size_t)(kb + j) * 256 + col];
        unsigned short h = f2bf(w);
        dst[j] = p ? f2bf(w - bf2f(h)) : h;
    }
}

// ---------------- conv1 GEMM on MFMA (split-bf16, ~fp32 accurate) ----------------
// grid (ceil(M/32), 2). Block 256 = 4 waves; wave w owns cols [w*64, w*64+64).
// Per wave: 2 M-tiles x 4 N-tiles of 16x16, K=256 in 8 steps of 32.
// acc = 32 AGPR; total regs ~110 -> 4 waves/SIMD (TLP hides load latency; no barriers).

__global__ __launch_bounds__(256) void gemm_conv1_mfma(
    const unsigned short* __restrict__ Xhi, const unsigned short* __restrict__ Xlo,
    const unsigned short* __restrict__ Wfrag,
    const float* __restrict__ bl, const float* __restrict__ br,
    unsigned short* __restrict__ Ylb, float* __restrict__ Yr, int M) {
    int tid = threadIdx.x;
    int wv = tid >> 6, l = tid & 63;
    int mat = blockIdx.y;
    int row0 = blockIdx.x * 32;
    int lrow = l & 15;
    int kg = (l >> 4) << 3;  // 0,8,16,24

    f32x4 acc[2][4];
#pragma unroll
    for (int i = 0; i < 2; ++i)
#pragma unroll
        for (int j = 0; j < 4; ++j) acc[i][j] = (f32x4){0.f, 0.f, 0.f, 0.f};

    size_t arow[2];
#pragma unroll
    for (int mt = 0; mt < 2; ++mt) {
        int r = row0 + mt * 16 + lrow;
        if (r > M - 1) r = M - 1;
        arow[mt] = (size_t)r * 256;
    }
    const bf16x8* bp = (const bf16x8*)Wfrag;
    size_t bhiB = ((size_t)(mat * 2 + 0) * 16 + wv * 4) * 8 * 64 + l;
    size_t bloB = ((size_t)(mat * 2 + 1) * 16 + wv * 4) * 8 * 64 + l;

    for (int ks = 0; ks < 8; ++ks) {
        int k0 = ks * 32 + kg;
        bf16x8 ah[2], al[2], bh[4], bw[4];
#pragma unroll
        for (int mt = 0; mt < 2; ++mt) {
            ah[mt] = *(const bf16x8*)(Xhi + arow[mt] + k0);
            al[mt] = *(const bf16x8*)(Xlo + arow[mt] + k0);
        }
#pragma unroll
        for (int nt = 0; nt < 4; ++nt) {
            bh[nt] = bp[bhiB + ((size_t)nt * 8 + ks) * 64];
            bw[nt] = bp[bloB + ((size_t)nt * 8 + ks) * 64];
        }
#pragma unroll
        for (int mt = 0; mt < 2; ++mt)
#pragma unroll
            for (int nt = 0; nt < 4; ++nt) {
                acc[mt][nt] = __builtin_amdgcn_mfma_f32_16x16x32_bf16(ah[mt], bh[nt], acc[mt][nt], 0, 0, 0);
                acc[mt][nt] = __builtin_amdgcn_mfma_f32_16x16x32_bf16(ah[mt], bw[nt], acc[mt][nt], 0, 0, 0);
                acc[mt][nt] = __builtin_amdgcn_mfma_f32_16x16x32_bf16(al[mt], bh[nt], acc[mt][nt], 0, 0, 0);
            }
    }

    const float* bias = mat ? br : bl;
    int col_l = l & 15;
    int rbase = (l >> 4) << 2;
#pragma unroll
    for (int nt = 0; nt < 4; ++nt) {
        int col = wv * 64 + nt * 16 + col_l;
        float bv = bias[col];
#pragma unroll
        for (int mt = 0; mt < 2; ++mt)
#pragma unroll
            for (int r = 0; r < 4; ++r) {
                int row = row0 + mt * 16 + rbase + r;
                if (row < M) {
                    float v = acc[mt][nt][r] + bv;
                    if (mat == 0)
                        Ylb[(size_t)row * 256 + col] = f2bf(v);
                    else
                        Yr[(size_t)row * 256 + col] = v;
                }
            }
    }
}

// ---------------- conv2 GEMM: X[M x 256] @ {Wl,Wr}[256 x 32] ----------------
// Yl written as bf16 (gathered operand of conv2), Yr fp32.

__global__ __launch_bounds__(256) void gemm_dual_32(
    const float* __restrict__ X,
    const float* __restrict__ Wl, const float* __restrict__ bl,
    const float* __restrict__ Wr, const float* __restrict__ br,
    unsigned short* __restrict__ Ylb, float* __restrict__ Yr, int M) {
    __shared__ float As[16][68];
    __shared__ float B2l[16][36];
    __shared__ float B2r[16][36];
    int tid = threadIdx.x;
    int tx = tid & 31;
    int ty = tid >> 5;
    int row0 = blockIdx.x * 64;
    float accl[8] = {0.f};
    float accr[8] = {0.f};
    int ar = tid >> 2;
    int ak = (tid & 3) << 2;

    for (int k0 = 0; k0 < 256; k0 += 16) {
        float4 av = make_float4(0.f, 0.f, 0.f, 0.f);
        if (row0 + ar < M)
            av = *(const float4*)(X + (size_t)(row0 + ar) * 256 + k0 + ak);
        As[ak + 0][ar] = av.x;
        As[ak + 1][ar] = av.y;
        As[ak + 2][ar] = av.z;
        As[ak + 3][ar] = av.w;
        if (tid < 128) {
            int bk2 = tid >> 3, bn2 = (tid & 7) << 2;
            *(float4*)&B2l[bk2][bn2] = *(const float4*)(Wl + (size_t)(k0 + bk2) * 32 + bn2);
        } else {
            int t2 = tid - 128;
            int bk2 = t2 >> 3, bn2 = (t2 & 7) << 2;
            *(float4*)&B2r[bk2][bn2] = *(const float4*)(Wr + (size_t)(k0 + bk2) * 32 + bn2);
        }
        __syncthreads();
#pragma unroll
        for (int k = 0; k < 16; ++k) {
            float blv = B2l[k][tx];
            float brv = B2r[k][tx];
#pragma unroll
            for (int i = 0; i < 8; ++i) {
                float a = As[k][ty * 8 + i];
                accl[i] = fmaf(a, blv, accl[i]);
                accr[i] = fmaf(a, brv, accr[i]);
            }
        }
        __syncthreads();
    }
#pragma unroll
    for (int i = 0; i < 8; ++i) {
        int row = row0 + ty * 8 + i;
        if (row < M) {
            Ylb[(size_t)row * 32 + tx] = f2bf(accl[i] + bl[tx]);
            Yr[(size_t)row * 32 + tx] = accr[i] + br[tx];
        }
    }
}

// ---------------- conv1 attention/aggregation (bf16 gather, 8-deep) ----------------

__global__ __launch_bounds__(256) void conv1_agg(
    const unsigned short* __restrict__ xlb, const float* __restrict__ xr,
    const float* __restrict__ att, const float* __restrict__ bias,
    const int* __restrict__ offsets, const int* __restrict__ csr_src,
    float* __restrict__ hout, int n) {
    int g = (blockIdx.x * blockDim.x + threadIdx.x) >> 6;
    if (g >= n) return;
    int lane = threadIdx.x & 63;
    int c0 = lane << 2;
    float4 xr4 = *(const float4*)(xr + (size_t)g * 256 + c0);
    float4 at4 = *(const float4*)(att + c0);
    float4 bb = *(const float4*)(bias + c0);
    int beg = offsets[g], end = offsets[g + 1];
    float m = -INFINITY, denom = 0.f;
    float4 acc = make_float4(0.f, 0.f, 0.f, 0.f);
    const ushort4* xb = (const ushort4*)xlb;
    int j = beg;
    for (; j + 8 <= end; j += 8) {
        ushort4 q[8];
#pragma unroll
        for (int u = 0; u < 8; ++u) {
            int s = csr_src[j + u];
            q[u] = xb[((size_t)s << 6) + lane];
        }
        float4 a[8];
        float p[8];
#pragma unroll
        for (int u = 0; u < 8; ++u) {
            a[u] = make_float4(bf2f(q[u].x), bf2f(q[u].y), bf2f(q[u].z), bf2f(q[u].w));
            p[u] = at4.x * lrelu(a[u].x + xr4.x) + at4.y * lrelu(a[u].y + xr4.y) +
                   at4.z * lrelu(a[u].z + xr4.z) + at4.w * lrelu(a[u].w + xr4.w);
        }
#pragma unroll
        for (int d = 1; d < 8; d <<= 1)
#pragma unroll
            for (int u = 0; u < 8; ++u) p[u] += __shfl_xor(p[u], d);
        float mn = m;
#pragma unroll
        for (int u = 0; u < 8; ++u) mn = fmaxf(mn, p[u]);
        float f = __expf(m - mn);
        float e[8];
        float es = 0.f;
#pragma unroll
        for (int u = 0; u < 8; ++u) { e[u] = __expf(p[u] - mn); es += e[u]; }
        float sx = 0.f, sy = 0.f, sz = 0.f, sw = 0.f;
#pragma unroll
        for (int u = 0; u < 8; ++u) {
            sx = fmaf(e[u], a[u].x, sx);
            sy = fmaf(e[u], a[u].y, sy);
            sz = fmaf(e[u], a[u].z, sz);
            sw = fmaf(e[u], a[u].w, sw);
        }
        acc.x = fmaf(acc.x, f, sx);
        acc.y = fmaf(acc.y, f, sy);
        acc.z = fmaf(acc.z, f, sz);
        acc.w = fmaf(acc.w, f, sw);
        denom = fmaf(denom, f, es);
        m = mn;
    }
    for (; j < end; ++j) {
        int s = csr_src[j];
        ushort4 qq = xb[((size_t)s << 6) + lane];
        float4 a4 = make_float4(bf2f(qq.x), bf2f(qq.y), bf2f(qq.z), bf2f(qq.w));
        float p = at4.x * lrelu(a4.x + xr4.x) + at4.y * lrelu(a4.y + xr4.y) +
                  at4.z * lrelu(a4.z + xr4.z) + at4.w * lrelu(a4.w + xr4.w);
        p += __shfl_xor(p, 1);
        p += __shfl_xor(p, 2);
        p += __shfl_xor(p, 4);
        float mn = fmaxf(m, p);
        float f = __expf(m - mn);
        float e = __expf(p - mn);
        acc.x = fmaf(acc.x, f, e * a4.x);
        acc.y = fmaf(acc.y, f, e * a4.y);
        acc.z = fmaf(acc.z, f, e * a4.z);
        acc.w = fmaf(acc.w, f, e * a4.w);
        denom = fmaf(denom, f, e);
        m = mn;
    }
    float inv = 1.f / (denom + 1e-16f);
    float4 o;
    o.x = elu_f(fmaf(acc.x, inv, bb.x));
    o.y = elu_f(fmaf(acc.y, inv, bb.y));
    o.z = elu_f(fmaf(acc.z, inv, bb.z));
    o.w = elu_f(fmaf(acc.w, inv, bb.w));
    *(float4*)(hout + (size_t)g * 256 + c0) = o;
}

// ---------------- conv2 agg + ELU + final linear fused (bf16 gather, 8-deep) ----------------

__global__ __launch_bounds__(256) void conv2_final(
    const unsigned short* __restrict__ xlb, const float* __restrict__ xr,
    const float* __restrict__ att, const float* __restrict__ bias,
    const int* __restrict__ offsets, const int* __restrict__ csr_src,
    const float* __restrict__ Wlin, const float* __restrict__ blin,
    float* __restrict__ out, int n) {
    __shared__ float Ws[2048];  // Wlin 32x64
    int tid = threadIdx.x;
    ((float4*)Ws)[tid] = ((const float4*)Wlin)[tid];
    ((float4*)Ws)[tid + 256] = ((const float4*)Wlin)[tid + 256];
    __syncthreads();
    int g = (blockIdx.x * blockDim.x + tid) >> 5;
    if (g >= n) return;
    int sl = tid & 31;
    float xrv = xr[(size_t)g * 32 + sl];
    float atv = att[sl];
    float bv = bias[sl];
    int beg = offsets[g], end = offsets[g + 1];
    float m = -INFINITY, denom = 0.f, acc = 0.f;
    int j = beg;
    for (; j + 8 <= end; j += 8) {
        float a[8], p[8];
#pragma unroll
        for (int u = 0; u < 8; ++u) {
            int s = csr_src[j + u];
            a[u] = bf2f(xlb[(size_t)s * 32 + sl]);
        }
#pragma unroll
        for (int u = 0; u < 8; ++u) p[u] = atv * lrelu(a[u] + xrv);
#pragma unroll
        for (int d = 1; d < 32; d <<= 1)
#pragma unroll
            for (int u = 0; u < 8; ++u) p[u] += __shfl_xor(p[u], d);
        float mn = m;
#pragma unroll
        for (int u = 0; u < 8; ++u) mn = fmaxf(mn, p[u]);
        float f = __expf(m - mn);
        float es = 0.f, sa = 0.f;
#pragma unroll
        for (int u = 0; u < 8; ++u) {
            float e = __expf(p[u] - mn);
            es += e;
            sa = fmaf(e, a[u], sa);
        }
        acc = fmaf(acc, f, sa);
        denom = fmaf(denom, f, es);
        m = mn;
    }
    for (; j < end; ++j) {
        int s = csr_src[j];
        float a = bf2f(xlb[(size_t)s * 32 + sl]);
        float p = atv * lrelu(a + xrv);
        p += __shfl_xor(p, 1);
        p += __shfl_xor(p, 2);
        p += __shfl_xor(p, 4);
        p += __shfl_xor(p, 8);
        p += __shfl_xor(p, 16);
        float mn = fmaxf(m, p);
        float f = __expf(m - mn);
        float e = __expf(p - mn);
        acc = fmaf(acc, f, e * a);
        denom = fmaf(denom, f, e);
        m = mn;
    }
    float inv = 1.f / (denom + 1e-16f);
    float hval = elu_f(fmaf(acc, inv, bv));
    int j0 = sl << 1;
    float o0 = blin[j0], o1 = blin[j0 + 1];
#pragma unroll
    for (int k = 0; k < 32; ++k) {
        float hk = __shfl(hval, k, 32);
        float2 w2 = *(float2*)&Ws[k * 64 + j0];
        o0 = fmaf(hk, w2.x, o0);
        o1 = fmaf(hk, w2.y, o1);
    }
    *(float2*)(out + (size_t)g * 64 + j0) = make_float2(o0, o1);
}

// ---------------- launch ----------------

extern "C" void kernel_launch(void* const* d_in, const int* in_sizes, int n_in,
                              void* d_out, int out_size, void* d_ws, size_t ws_size,
                              hipStream_t stream) {
    const float* x    = (const float*)d_in[0];
    const int*   ei   = (const int*)d_in[1];
    const float* W1l  = (const float*)d_in[2];
    const float* b1l  = (const float*)d_in[3];
    const float* W1r  = (const float*)d_in[4];
    const float* b1r  = (const float*)d_in[5];
    const float* att1 = (const float*)d_in[6];
    const float* bias1= (const float*)d_in[7];
    const float* W2l  = (const float*)d_in[8];
    const float* b2l  = (const float*)d_in[9];
    const float* W2r  = (const float*)d_in[10];
    const float* b2r  = (const float*)d_in[11];
    const float* att2 = (const float*)d_in[12];
    const float* bias2= (const float*)d_in[13];
    const float* Wlin = (const float*)d_in[14];
    const float* blin = (const float*)d_in[15];
    float* out = (float*)d_out;

    char* p = (char*)d_ws;
    auto alloc = [&](size_t bytes) {
        char* r = p;
        p += (bytes + 255) & ~(size_t)255;
        return r;
    };
    int* offsets = (int*)alloc((size_t)(N_NODES + 1) * 4);
    int* cursor  = (int*)alloc((size_t)N_NODES * 4);  // doubles as counts
    int* bsums   = (int*)alloc((size_t)(SCAN_NB + 1) * 4);
    int* csr_src = (int*)alloc((size_t)N_EDGES * 4);
    unsigned short* xl1b = (unsigned short*)alloc((size_t)N_NODES * 256 * 2);
    float* xr1 = (float*)alloc((size_t)N_NODES * 256 * 4);
    // X split region (dead after gemm_conv1_mfma) -> h1 aliases it
    unsigned short* xhi = (unsigned short*)alloc((size_t)N_NODES * 256 * 2);
    unsigned short* xlo = (unsigned short*)alloc((size_t)N_NODES * 256 * 2);
    unsigned short* wfrag = (unsigned short*)alloc((size_t)2 * 2 * 16 * 8 * 64 * 8 * 2);
    unsigned short* xl2b = (unsigned short*)alloc((size_t)N_NODES * 32 * 2);
    float* h1 = (float*)xhi;             // 51.2 MB alias over xhi+xlo
    float* xr2 = xr1;                    // xr1 dead after conv1_agg

    const int* srcp = ei;
    const int* dstp = ei + N_EDGES;

    hipMemsetAsync(cursor, 0, (size_t)N_NODES * 4, stream);
    hist_kernel<<<(N_EDGES + 255) / 256, 256, 0, stream>>>(dstp, cursor, N_EDGES);
    scan_blk<<<SCAN_NB, 1024, 0, stream>>>(cursor, offsets, bsums, N_NODES);
    scan_tops<<<1, 64, 0, stream>>>(bsums, SCAN_NB);
    scan_add<<<SCAN_NB, 1024, 0, stream>>>(bsums, offsets, cursor, N_NODES, SCAN_NB);
    scatter_kernel<<<(N_EDGES + 255) / 256, 256, 0, stream>>>(srcp, dstp, cursor, csr_src, N_EDGES);

    presplit<<<(N_NODES * 256 / 4 + 255) / 256, 256, 0, stream>>>(x, xhi, xlo, N_NODES * 256 / 4);
    wprep<<<128, 256, 0, stream>>>(W1l, W1r, wfrag);

    dim3 gg((N_NODES + 31) / 32, 2);
    gemm_conv1_mfma<<<gg, 256, 0, stream>>>(xhi, xlo, wfrag, b1l, b1r, xl1b, xr1, N_NODES);
    conv1_agg<<<(N_NODES * 64 + 255) / 256, 256, 0, stream>>>(xl1b, xr1, att1, bias1,
                                                              offsets, csr_src, h1, N_NODES);
    gemm_dual_32<<<(N_NODES + 63) / 64, 256, 0, stream>>>(h1, W2l, b2l, W2r, b2r, xl2b, xr2, N_NODES);
    conv2_final<<<(N_NODES * 32 + 255) / 256, 256, 0, stream>>>(xl2b, xr2, att2, bias2,
                                                                offsets, csr_src,
                                                                Wlin, blin, out, N_NODES);
}